// Round 3
// baseline (858.387 us; speedup 1.0000x reference)
//
#include <hip/hip_runtime.h>
#include <hip/hip_bf16.h>

#define Bb 128
#define Tt 1024
#define Nn 128
#define Ss 256
#define NEGF (-1e30f)
#define D9 9.0f   // fixed log-domain shift per active step (absorbed into c at the end)

typedef __attribute__((ext_vector_type(8))) short short8;  // 8 bf16 (4 VGPRs) — MFMA A/B frag
typedef __attribute__((ext_vector_type(4))) float f32x4;   // MFMA C/D frag

__device__ __forceinline__ short bf16b(float f) {
    __hip_bfloat16 h = __float2bfloat16(f);
    return *reinterpret_cast<short*>(&h);
}

// blocks 0..7:  FCC, 16 batches each, MFMA 16x16x32_bf16, E in registers
// blocks 8..39: FAC, 4 batches each (1 wave per batch, wave-synchronous)
__global__ __launch_bounds__(256) void asg_main(
    const float* __restrict__ trans, const float* __restrict__ x,
    const int* __restrict__ targets, const int* __restrict__ ilen,
    const int* __restrict__ tlen,
    float* __restrict__ fcc_out, float* __restrict__ fac_out)
{
    // u_t double buffer, bf16, [buf][g][j] with j-stride 136 (pad 8; 272 B = 16*17 keeps 16B align)
    __shared__ __align__(16) short ut[2][16][136];
    __shared__ float wred[4][16];

    const int tid  = threadIdx.x;
    const int q    = tid >> 6;      // wave id
    const int lane = tid & 63;
    const int g    = lane & 15;     // batch-in-group (B frag col / D frag col)
    const int quad = lane >> 4;

    if (blockIdx.x < 8) {
        // ================= FCC =================
        const int b   = (blockIdx.x << 4) + g;
        const int len = ilen[b];
        const float* xb = x + (size_t)b * Tt * Nn;

        // E A-fragments: wave q owns rows [32q, 32q+32) -> 2 M-tiles of 16.
        // A[m=lane&15][k=quad*8+jj] per K-chunk kc (K=32 each).
        short8 ea[2][4];
        #pragma unroll
        for (int mt = 0; mt < 2; ++mt) {
            const float* tr = trans + (size_t)(32 * q + 16 * mt + g) * Nn + quad * 8;
            #pragma unroll
            for (int kc = 0; kc < 4; ++kc) {
                short8 v;
                #pragma unroll
                for (int jj = 0; jj < 8; ++jj)
                    v[jj] = bf16b(__expf(tr[kc * 32 + jj]));
                ea[mt][kc] = v;
            }
        }

        const int j0_ = 32 * q + 4 * quad;   // D-layout row base (mt=1 adds 16)

        // u0 = exp(x[0]) (c = 0)
        float uprev[2][4];
        #pragma unroll
        for (int mt = 0; mt < 2; ++mt) {
            const int j0 = j0_ + 16 * mt;
            float4 xv = *(const float4*)(xb + j0);
            uprev[mt][0] = __expf(xv.x); uprev[mt][1] = __expf(xv.y);
            uprev[mt][2] = __expf(xv.z); uprev[mt][3] = __expf(xv.w);
            short4 s4;
            s4.x = bf16b(uprev[mt][0]); s4.y = bf16b(uprev[mt][1]);
            s4.z = bf16b(uprev[mt][2]); s4.w = bf16b(uprev[mt][3]);
            *reinterpret_cast<short4*>(&ut[0][g][j0]) = s4;
        }

        // w for t=1 precomputed; x-ring holds x[2]
        float wc[2][4];
        float4 xs[2];
        #pragma unroll
        for (int mt = 0; mt < 2; ++mt) {
            const int j0 = j0_ + 16 * mt;
            float4 xv = *(const float4*)(xb + Nn + j0);
            wc[mt][0] = __expf(xv.x - D9); wc[mt][1] = __expf(xv.y - D9);
            wc[mt][2] = __expf(xv.z - D9); wc[mt][3] = __expf(xv.w - D9);
            xs[mt] = *(const float4*)(xb + 2 * Nn + j0);
        }
        float c = 0.0f;
        __syncthreads();

        for (int t = 1; t < Tt; ++t) {
            // renorm apply (max measured at t-1, t-1 ≡ 7 mod 8)
            if ((t & 7) == 0) {
                float m = fmaxf(fmaxf(wred[0][g], wred[1][g]),
                                fmaxf(wred[2][g], wred[3][g]));
                if (t < len) {
                    float invm = 1.0f / m;
                    #pragma unroll
                    for (int mt = 0; mt < 2; ++mt)
                        #pragma unroll
                        for (int r = 0; r < 4; ++r) wc[mt][r] *= invm;
                    c += __logf(m);
                }
            }

            // B-frags: u_{t-1}[g][k], k = kc*32 + quad*8 + jj  (same k-map as A)
            const short* up = &ut[(t - 1) & 1][g][0] + quad * 8;
            short8 bf0 = *(const short8*)(up);
            short8 bf1 = *(const short8*)(up + 32);
            short8 bf2 = *(const short8*)(up + 64);
            short8 bf3 = *(const short8*)(up + 96);

            f32x4 a0 = {0.f, 0.f, 0.f, 0.f}, a1 = {0.f, 0.f, 0.f, 0.f};
            a0 = __builtin_amdgcn_mfma_f32_16x16x32_bf16(ea[0][0], bf0, a0, 0, 0, 0);
            a1 = __builtin_amdgcn_mfma_f32_16x16x32_bf16(ea[1][0], bf0, a1, 0, 0, 0);
            a0 = __builtin_amdgcn_mfma_f32_16x16x32_bf16(ea[0][1], bf1, a0, 0, 0, 0);
            a1 = __builtin_amdgcn_mfma_f32_16x16x32_bf16(ea[1][1], bf1, a1, 0, 0, 0);
            a0 = __builtin_amdgcn_mfma_f32_16x16x32_bf16(ea[0][2], bf2, a0, 0, 0, 0);
            a1 = __builtin_amdgcn_mfma_f32_16x16x32_bf16(ea[1][2], bf2, a1, 0, 0, 0);
            a0 = __builtin_amdgcn_mfma_f32_16x16x32_bf16(ea[0][3], bf3, a0, 0, 0, 0);
            a1 = __builtin_amdgcn_mfma_f32_16x16x32_bf16(ea[1][3], bf3, a1, 0, 0, 0);

            const bool act = (t < len);
            float un[2][4];
            #pragma unroll
            for (int r = 0; r < 4; ++r) {
                un[0][r] = act ? wc[0][r] * a0[r] : uprev[0][r];
                un[1][r] = act ? wc[1][r] * a1[r] : uprev[1][r];
            }
            #pragma unroll
            for (int mt = 0; mt < 2; ++mt) {
                #pragma unroll
                for (int r = 0; r < 4; ++r) uprev[mt][r] = un[mt][r];
                short4 s4;
                s4.x = bf16b(un[mt][0]); s4.y = bf16b(un[mt][1]);
                s4.z = bf16b(un[mt][2]); s4.w = bf16b(un[mt][3]);
                *reinterpret_cast<short4*>(&ut[t & 1][g][j0_ + 16 * mt]) = s4;
            }

            // off-critical-path: w for t+1 from ring, refill ring with x[t+2]
            #pragma unroll
            for (int mt = 0; mt < 2; ++mt) {
                wc[mt][0] = __expf(xs[mt].x - D9);
                wc[mt][1] = __expf(xs[mt].y - D9);
                wc[mt][2] = __expf(xs[mt].z - D9);
                wc[mt][3] = __expf(xs[mt].w - D9);
            }
            const int tn = (t + 2 < Tt) ? t + 2 : Tt - 1;
            #pragma unroll
            for (int mt = 0; mt < 2; ++mt)
                xs[mt] = *(const float4*)(xb + (size_t)tn * Nn + j0_ + 16 * mt);

            // renorm measure every 8 steps
            if ((t & 7) == 7) {
                float mm = un[0][0];
                mm = fmaxf(mm, un[0][1]); mm = fmaxf(mm, un[0][2]); mm = fmaxf(mm, un[0][3]);
                mm = fmaxf(mm, un[1][0]); mm = fmaxf(mm, un[1][1]);
                mm = fmaxf(mm, un[1][2]); mm = fmaxf(mm, un[1][3]);
                mm = fmaxf(mm, __shfl_xor(mm, 16));
                mm = fmaxf(mm, __shfl_xor(mm, 32));
                if (lane < 16) wred[q][lane] = mm;
            }
            __syncthreads();
        }

        // R2 bug fix: every ACTIVE step multiplies u by exp(-D9); absorb the
        // count-based offset into c once (len-1 active steps: t = 1..len-1).
        c += D9 * (float)(len - 1);

        // fcc = c + log(sum_j u[j][g])
        float s = 0.f;
        #pragma unroll
        for (int mt = 0; mt < 2; ++mt)
            #pragma unroll
            for (int r = 0; r < 4; ++r) s += uprev[mt][r];
        s += __shfl_xor(s, 16);
        s += __shfl_xor(s, 32);
        if (lane < 16) wred[q][lane] = s;
        __syncthreads();
        if (tid < 16) {
            float tot = wred[0][tid] + wred[1][tid] + wred[2][tid] + wred[3][tid];
            fcc_out[(blockIdx.x << 4) + tid] = c + __logf(tot);
        }
    } else {
        // ================= FAC (1 wave per batch, no barriers) =================
        const int b   = ((blockIdx.x - 8) << 2) + q;
        const int len = ilen[b];
        const int tl  = tlen[b];
        const float* xb = x + (size_t)b * Tt * Nn;

        int   tgi[4];
        float st[4], ntr[4], bt[4];
        #pragma unroll
        for (int r = 0; r < 4; ++r) {
            const int s = (lane << 2) + r;
            const int tgv = targets[b * Ss + s];
            const int pg  = (s == 0) ? tgv : targets[b * Ss + s - 1];
            tgi[r] = tgv;
            st[r]  = trans[tgv * Nn + tgv];
            ntr[r] = trans[tgv * Nn + pg];
            bt[r]  = (s == 0) ? xb[tgv] : NEGF;
        }
        // em ring, depth 4
        float em[4][4];
        #pragma unroll
        for (int d = 0; d < 4; ++d) {
            int tt = d + 1; if (tt > Tt - 1) tt = Tt - 1;
            #pragma unroll
            for (int r = 0; r < 4; ++r) em[d][r] = xb[(size_t)tt * Nn + tgi[r]];
        }

        for (int t = 1; t < Tt; ++t) {
            const int d = (t - 1) & 3;
            float bup = __shfl_up(bt[3], 1);
            float prev0 = (lane == 0) ? NEGF : bup;
            float nb[4];
            #pragma unroll
            for (int r = 0; r < 4; ++r) {
                float prev = (r == 0) ? prev0 : bt[r - 1];
                float aa = bt[r] + st[r];
                float bb = prev + ntr[r];
                float hi = fmaxf(aa, bb), lo = fminf(aa, bb);
                nb[r] = em[d][r] + hi + __logf(1.0f + __expf(lo - hi));
            }
            if (t < len) {
                #pragma unroll
                for (int r = 0; r < 4; ++r) bt[r] = nb[r];
            }
            int tn = t + 4; if (tn > Tt - 1) tn = Tt - 1;
            #pragma unroll
            for (int r = 0; r < 4; ++r) em[d][r] = xb[(size_t)tn * Nn + tgi[r]];
        }
        #pragma unroll
        for (int r = 0; r < 4; ++r)
            if ((lane << 2) + r == tl - 1) fac_out[b] = bt[r];
    }
}

__global__ __launch_bounds__(128) void reduce_kernel(const float* __restrict__ fcc,
                                                     const float* __restrict__ fac,
                                                     float* __restrict__ out) {
    __shared__ float r2[2];
    int tid = threadIdx.x;
    float v = fcc[tid] - fac[tid];
    #pragma unroll
    for (int o = 32; o > 0; o >>= 1) v += __shfl_xor(v, o);
    if ((tid & 63) == 0) r2[tid >> 6] = v;
    __syncthreads();
    if (tid == 0) out[0] = (r2[0] + r2[1]) * (1.0f / Bb);
}

extern "C" void kernel_launch(void* const* d_in, const int* in_sizes, int n_in,
                              void* d_out, int out_size, void* d_ws, size_t ws_size,
                              hipStream_t stream) {
    const float* trans   = (const float*)d_in[0];
    const float* x       = (const float*)d_in[1];
    const int*   targets = (const int*)d_in[2];
    const int*   ilen    = (const int*)d_in[3];
    const int*   tlen    = (const int*)d_in[4];
    float* out = (float*)d_out;

    float* fcc = (float*)d_ws;       // B floats
    float* fac = fcc + Bb;           // B floats

    asg_main<<<8 + Bb / 4, 256, 0, stream>>>(trans, x, targets, ilen, tlen, fcc, fac);
    reduce_kernel<<<1, 128, 0, stream>>>(fcc, fac, out);
}